// Round 2
// baseline (926.579 us; speedup 1.0000x reference)
//
#include <hip/hip_runtime.h>
#include <hip/hip_bf16.h>

// Problem constants: B=4, S=2048, D=1024, H=16, dk=64
#define SEQ   2048
#define NB    4
#define NH    16
#define DK    64
#define DM    1024
#define MROWS (NB * SEQ)   // 8192

typedef __bf16 bf16_t;
typedef __bf16 bf16x8 __attribute__((ext_vector_type(8)));
typedef __bf16 bf16x4 __attribute__((ext_vector_type(4)));
typedef float  f32x4  __attribute__((ext_vector_type(4)));

#define MFMA16(a, b, c) __builtin_amdgcn_mfma_f32_16x16x32_bf16((a), (b), (c), 0, 0, 0)

// ---------------------------------------------------------------------------
// fp32 -> bf16 conversion (inputs arrive as float32 per the reference)
// ---------------------------------------------------------------------------
__global__ __launch_bounds__(256) void cvt_kernel(
    const float* __restrict__ in, bf16_t* __restrict__ out, int n)
{
    int i = (blockIdx.x * 256 + threadIdx.x) * 4;
    if (i + 3 < n) {
        const float4 v = *(const float4*)(in + i);
        bf16x4 o;
        o[0] = (bf16_t)v.x; o[1] = (bf16_t)v.y;
        o[2] = (bf16_t)v.z; o[3] = (bf16_t)v.w;
        *(bf16x4*)(out + i) = o;
    }
}

// ---------------------------------------------------------------------------
// RoPE table: tab[s*32+i] = (cos(s*f_i), sin(s*f_i)), f_i = 10000^(-i/32)
// ---------------------------------------------------------------------------
__global__ void rope_table_kernel(float2* __restrict__ tab) {
    int idx = blockIdx.x * 256 + threadIdx.x;
    if (idx >= SEQ * 32) return;
    int s = idx >> 5, i = idx & 31;
    float freq = powf(10000.0f, -(float)i / 32.0f);
    float a = (float)s * freq;
    tab[idx] = make_float2(cosf(a), sinf(a));
}

// ---------------------------------------------------------------------------
// GEMM: out = X(MxK) @ W(KxN), bf16 in, fp32 accum.
// Tile 64x64, 4 waves, each wave does 16 rows x 64 cols via 16x16x32 MFMA.
// mode 0: Q epilogue (RoPE, store bf16 [B,H,S,dk])
// mode 1: K epilogue (RoPE, store bf16 [B,H,S,dk])
// mode 2: V epilogue (store bf16 transposed [B,H,dk,S])
// mode 3: plain row-major store as FLOAT (final projection -> d_out)
// ---------------------------------------------------------------------------
#define LDP 40  // padded LDS row length (elements)

__global__ __launch_bounds__(256) void gemm_ep_kernel(
    const bf16_t* __restrict__ X, const bf16_t* __restrict__ W,
    void* __restrict__ out_v, const float2* __restrict__ rope,
    int M, int N, int K, int mode)
{
    __shared__ __align__(16) bf16_t As[64 * LDP];
    __shared__ __align__(16) bf16_t Bs[64 * LDP];

    const int tid  = threadIdx.x;
    const int lane = tid & 63;
    const int wave = tid >> 6;
    const int l    = lane & 15;
    const int quad = lane >> 4;

    const int nTilesN = N >> 6;
    const int bm = blockIdx.x / nTilesN;
    const int bn = blockIdx.x % nTilesN;
    const int m0 = bm << 6;
    const int n0 = bn << 6;

    f32x4 acc[4] = {};

    // staging indices: A tile 64x32 (256 thr x 8 elem), B tile 32x64
    const int ar  = tid >> 2;        // 0..63
    const int ac  = (tid & 3) << 3;  // 0,8,16,24
    const int bk  = tid >> 3;        // 0..31
    const int bn8 = (tid & 7) << 3;  // 0..56

    for (int k0 = 0; k0 < K; k0 += 32) {
        bf16x8 av = *(const bf16x8*)(X + (size_t)(m0 + ar) * K + k0 + ac);
        bf16x8 bv = *(const bf16x8*)(W + (size_t)(k0 + bk) * N + n0 + bn8);
        *(bf16x8*)(As + ar * LDP + ac) = av;
#pragma unroll
        for (int j = 0; j < 8; ++j)  // transpose-on-store: Bs[n][k]
            Bs[(bn8 + j) * LDP + bk] = bv[j];
        __syncthreads();

        bf16x8 a = *(const bf16x8*)(As + (wave * 16 + l) * LDP + quad * 8);
#pragma unroll
        for (int n = 0; n < 4; ++n) {
            bf16x8 b = *(const bf16x8*)(Bs + (n * 16 + l) * LDP + quad * 8);
            acc[n] = MFMA16(a, b, acc[n]);
        }
        __syncthreads();
    }

    // epilogue: C layout row = quad*4+r, col = l (within each 16-col block)
#pragma unroll
    for (int n = 0; n < 4; ++n) {
#pragma unroll
        for (int r = 0; r < 4; ++r) {
            const int m  = m0 + wave * 16 + quad * 4 + r;
            const int nn = n0 + n * 16 + l;
            float v = acc[n][r];
            if (mode == 3) {
                ((float*)out_v)[(size_t)m * N + nn] = v;
            } else {
                bf16_t* out = (bf16_t*)out_v;
                const int b = m >> 11, s = m & (SEQ - 1);
                const int h = nn >> 6, d = nn & (DK - 1);
                if (mode == 2) {
                    // V transposed: [B,H,dk,S]
                    out[(((size_t)(b * NH + h)) * DK + d) * SEQ + s] = (bf16_t)v;
                } else {
                    // RoPE: pair (2i,2i+1) are adjacent cols = adjacent lanes
                    float pv = __shfl_xor(v, 1);
                    float2 cs = rope[s * 32 + (d >> 1)];
                    float res = (d & 1) ? (v * cs.x + pv * cs.y)
                                        : (v * cs.x - pv * cs.y);
                    out[(((size_t)(b * NH + h)) * SEQ + s) * DK + d] = (bf16_t)res;
                }
            }
        }
    }
}

// ---------------------------------------------------------------------------
// Causal flash attention. Q,K: [B,H,S,dk]; Vt: [B,H,dk,S]; O: [B,S,D] bf16.
// One wave per 16 queries; workgroup = 4 waves = 64 queries of one (b,h).
// Key chunks of 32, online softmax, P through LDS (C-layout -> A-layout).
// ---------------------------------------------------------------------------
__global__ __launch_bounds__(256) void attn_kernel(
    const bf16_t* __restrict__ Q, const bf16_t* __restrict__ K,
    const bf16_t* __restrict__ Vt, bf16_t* __restrict__ O)
{
    __shared__ __align__(16) bf16_t Pl[4][16 * LDP];

    const int bh   = blockIdx.y;          // b*NH + h
    const int wave = threadIdx.x >> 6;
    const int lane = threadIdx.x & 63;
    const int l    = lane & 15;
    const int quad = lane >> 4;
    const int q0   = blockIdx.x * 64 + wave * 16;

    bf16_t* P = Pl[wave];
    const bf16_t* Qb = Q  + (size_t)bh * SEQ * DK;
    const bf16_t* Kb = K  + (size_t)bh * SEQ * DK;
    const bf16_t* Vb = Vt + (size_t)bh * DK * SEQ;

    const bf16x8 qa0 = *(const bf16x8*)(Qb + (q0 + l) * DK + quad * 8);
    const bf16x8 qa1 = *(const bf16x8*)(Qb + (q0 + l) * DK + 32 + quad * 8);

    float mI[4], lI[4];
    f32x4 o[4] = {};
#pragma unroll
    for (int r = 0; r < 4; ++r) { mI[r] = -3e38f; lI[r] = 0.0f; }

    const int q_hi = q0 + 15;
    for (int c = 0; c <= q_hi; c += 32) {
        f32x4 sc0 = {}, sc1 = {};
        {
            bf16x8 kb;
            kb = *(const bf16x8*)(Kb + (c + l) * DK + quad * 8);
            sc0 = MFMA16(qa0, kb, sc0);
            kb = *(const bf16x8*)(Kb + (c + l) * DK + 32 + quad * 8);
            sc0 = MFMA16(qa1, kb, sc0);
            kb = *(const bf16x8*)(Kb + (c + 16 + l) * DK + quad * 8);
            sc1 = MFMA16(qa0, kb, sc1);
            kb = *(const bf16x8*)(Kb + (c + 16 + l) * DK + 32 + quad * 8);
            sc1 = MFMA16(qa1, kb, sc1);
        }
        const bool tail = (c + 31 > q0);
        float alpha[4];
#pragma unroll
        for (int r = 0; r < 4; ++r) {
            float s0 = sc0[r] * 0.125f;
            float s1 = sc1[r] * 0.125f;
            if (tail) {
                const int rq = q0 + quad * 4 + r;
                if (c + l      > rq) s0 = -3e38f;
                if (c + 16 + l > rq) s1 = -3e38f;
            }
            float mx = fmaxf(s0, s1);
            mx = fmaxf(mx, __shfl_xor(mx, 1));
            mx = fmaxf(mx, __shfl_xor(mx, 2));
            mx = fmaxf(mx, __shfl_xor(mx, 4));
            mx = fmaxf(mx, __shfl_xor(mx, 8));
            const float mnew = fmaxf(mI[r], mx);
            alpha[r] = __expf(mI[r] - mnew);
            mI[r] = mnew;
            const float p0 = __expf(s0 - mnew);
            const float p1 = __expf(s1 - mnew);
            float sum = p0 + p1;
            sum += __shfl_xor(sum, 1);
            sum += __shfl_xor(sum, 2);
            sum += __shfl_xor(sum, 4);
            sum += __shfl_xor(sum, 8);
            lI[r] = lI[r] * alpha[r] + sum;
            P[(quad * 4 + r) * LDP + l]      = (bf16_t)p0;
            P[(quad * 4 + r) * LDP + 16 + l] = (bf16_t)p1;
            o[0][r] *= alpha[r];
            o[1][r] *= alpha[r];
            o[2][r] *= alpha[r];
            o[3][r] *= alpha[r];
        }
        // P: C-layout in LDS -> A-layout frag (same-wave DS ops are in order)
        const bf16x8 pa = *(const bf16x8*)(P + l * LDP + quad * 8);
#pragma unroll
        for (int n = 0; n < 4; ++n) {
            bf16x8 vb = *(const bf16x8*)(Vb + (size_t)(n * 16 + l) * SEQ + c + quad * 8);
            o[n] = MFMA16(pa, vb, o[n]);
        }
    }

    const int b = bh >> 4, h = bh & 15;
#pragma unroll
    for (int n = 0; n < 4; ++n) {
#pragma unroll
        for (int r = 0; r < 4; ++r) {
            const int s = q0 + quad * 4 + r;
            const float v = o[n][r] / lI[r];
            O[((size_t)(b * SEQ + s)) * DM + h * DK + n * 16 + l] = (bf16_t)v;
        }
    }
}

// ---------------------------------------------------------------------------
extern "C" void kernel_launch(void* const* d_in, const int* in_sizes, int n_in,
                              void* d_out, int out_size, void* d_ws, size_t ws_size,
                              hipStream_t stream)
{
    const float* x  = (const float*)d_in[0];
    const float* Wq = (const float*)d_in[1];
    const float* Wk = (const float*)d_in[2];
    const float* Wv = (const float*)d_in[3];
    const float* Wo = (const float*)d_in[4];
    float* out = (float*)d_out;

    char* ws = (char*)d_ws;
    float2* rope = (float2*)ws;                        // 2048*32*8 = 512 KiB
    const size_t TEN = (size_t)MROWS * DM;             // 8,388,608 elems
    const size_t WEL = (size_t)DM * DM;                // 1,048,576 elems
    bf16_t* xb  = (bf16_t*)(ws + (1 << 19));
    bf16_t* Wqb = xb  + TEN;
    bf16_t* Wkb = Wqb + WEL;
    bf16_t* Wvb = Wkb + WEL;
    bf16_t* Wob = Wvb + WEL;
    bf16_t* Qt  = Wob + WEL;
    bf16_t* Kt  = Qt + TEN;
    bf16_t* Vt  = Kt + TEN;
    bf16_t* Ot  = Vt + TEN;                            // total ~88.5 MB

    rope_table_kernel<<<(SEQ * 32 + 255) / 256, 256, 0, stream>>>(rope);

    cvt_kernel<<<(int)(TEN / 4 / 256), 256, 0, stream>>>(x,  xb,  (int)TEN);
    cvt_kernel<<<(int)(WEL / 4 / 256), 256, 0, stream>>>(Wq, Wqb, (int)WEL);
    cvt_kernel<<<(int)(WEL / 4 / 256), 256, 0, stream>>>(Wk, Wkb, (int)WEL);
    cvt_kernel<<<(int)(WEL / 4 / 256), 256, 0, stream>>>(Wv, Wvb, (int)WEL);
    cvt_kernel<<<(int)(WEL / 4 / 256), 256, 0, stream>>>(Wo, Wob, (int)WEL);

    const int gemm_grid = (MROWS / 64) * (DM / 64);    // 128*16 = 2048
    gemm_ep_kernel<<<gemm_grid, 256, 0, stream>>>(xb, Wqb, Qt, rope, MROWS, DM, DM, 0);
    gemm_ep_kernel<<<gemm_grid, 256, 0, stream>>>(xb, Wkb, Kt, rope, MROWS, DM, DM, 1);
    gemm_ep_kernel<<<gemm_grid, 256, 0, stream>>>(xb, Wvb, Vt, rope, MROWS, DM, DM, 2);

    attn_kernel<<<dim3(SEQ / 64, NB * NH), 256, 0, stream>>>(Qt, Kt, Vt, Ot);

    gemm_ep_kernel<<<gemm_grid, 256, 0, stream>>>(Ot, Wob, d_out, rope, MROWS, DM, DM, 3);
}

// Round 3
// 786.305 us; speedup vs baseline: 1.1784x; 1.1784x over previous
//
#include <hip/hip_runtime.h>
#include <hip/hip_bf16.h>

// Problem constants: B=4, S=2048, D=1024, H=16, dk=64
#define SEQ   2048
#define NB    4
#define NH    16
#define DK    64
#define DM    1024
#define MROWS (NB * SEQ)   // 8192

typedef __bf16 bf16_t;
typedef __bf16 bf16x8 __attribute__((ext_vector_type(8)));
typedef __bf16 bf16x4 __attribute__((ext_vector_type(4)));
typedef float  f32x4  __attribute__((ext_vector_type(4)));

#define MFMA16(a, b, c) __builtin_amdgcn_mfma_f32_16x16x32_bf16((a), (b), (c), 0, 0, 0)

// ---------------------------------------------------------------------------
// fp32 -> bf16 conversion (x)
// ---------------------------------------------------------------------------
__global__ __launch_bounds__(256) void cvt_kernel(
    const float* __restrict__ in, bf16_t* __restrict__ out, int n)
{
    int i = (blockIdx.x * 256 + threadIdx.x) * 4;
    if (i + 3 < n) {
        const float4 v = *(const float4*)(in + i);
        bf16x4 o;
        o[0] = (bf16_t)v.x; o[1] = (bf16_t)v.y;
        o[2] = (bf16_t)v.z; o[3] = (bf16_t)v.w;
        *(bf16x4*)(out + i) = o;
    }
}

// ---------------------------------------------------------------------------
// Weight transpose + cast: Wt[n][k] = (bf16)W[k][n].  32x32 tiles via LDS.
// ---------------------------------------------------------------------------
__global__ __launch_bounds__(256) void wtr_kernel(
    const float* __restrict__ W, bf16_t* __restrict__ Wt)
{
    __shared__ float T[32][33];
    const int tk0 = (blockIdx.x >> 5) << 5;
    const int tn0 = (blockIdx.x & 31) << 5;
    const int r = threadIdx.x >> 5, c = threadIdx.x & 31;
#pragma unroll
    for (int i = 0; i < 4; ++i)
        T[r + i * 8][c] = W[(size_t)(tk0 + r + i * 8) * DM + tn0 + c];
    __syncthreads();
#pragma unroll
    for (int i = 0; i < 4; ++i)
        Wt[(size_t)(tn0 + r + i * 8) * DM + tk0 + c] = (bf16_t)T[c][r + i * 8];
}

// ---------------------------------------------------------------------------
// RoPE table: tab[s*32+i] = (cos, sin) of s * 10000^(-i/32)
// ---------------------------------------------------------------------------
__global__ void rope_table_kernel(float2* __restrict__ tab) {
    int idx = blockIdx.x * 256 + threadIdx.x;
    if (idx >= SEQ * 32) return;
    int s = idx >> 5, i = idx & 31;
    float freq = powf(10000.0f, -(float)i / 32.0f);
    float a = (float)s * freq;
    tab[idx] = make_float2(cosf(a), sinf(a));
}

// ---------------------------------------------------------------------------
// GEMM: C = X(8192x1024) @ Wt^T, Wt stored [N][K] row-major (pre-transposed).
// 128x128x32 tile, 4 waves (2x2), each wave 4x4 16x16 tiles.
// mode 0: RoPE + 1/8 scale -> Qt [B,H,S,dk] bf16
// mode 1: RoPE            -> Kt [B,H,S,dk] bf16
// mode 2: transposed C (swap MFMA operands) -> Vt [B,H,dk,S] bf16
// mode 3: plain fp32 row-major -> d_out
// ---------------------------------------------------------------------------
__global__ __launch_bounds__(256) void gemm_ep_kernel(
    const bf16_t* __restrict__ X, const bf16_t* __restrict__ Wt,
    void* __restrict__ out_v, const float2* __restrict__ rope, int mode)
{
    __shared__ __align__(16) bf16_t As[128 * 32];
    __shared__ __align__(16) bf16_t Bs[128 * 32];

    const int tid  = threadIdx.x;
    const int lane = tid & 63;
    const int wave = tid >> 6;
    const int wm   = wave & 1, wn = wave >> 1;
    const int l    = lane & 15;
    const int quad = lane >> 4;

    const int m0 = (blockIdx.x >> 3) << 7;   // N/128 = 8 tiles in n
    const int n0 = (blockIdx.x & 7) << 7;

    const int sr = tid >> 2;          // 0..63
    const int sc = (tid & 3) << 3;    // 0,8,16,24

    f32x4 acc[4][4] = {};
    const bool tr = (mode == 2);

    for (int k0 = 0; k0 < DM; k0 += 32) {
        bf16x8 a0 = *(const bf16x8*)(X  + (size_t)(m0 + sr) * DM + k0 + sc);
        bf16x8 a1 = *(const bf16x8*)(X  + (size_t)(m0 + 64 + sr) * DM + k0 + sc);
        bf16x8 b0 = *(const bf16x8*)(Wt + (size_t)(n0 + sr) * DM + k0 + sc);
        bf16x8 b1 = *(const bf16x8*)(Wt + (size_t)(n0 + 64 + sr) * DM + k0 + sc);
        __syncthreads();
        *(bf16x8*)(As + sr * 32 + sc)        = a0;
        *(bf16x8*)(As + (64 + sr) * 32 + sc) = a1;
        *(bf16x8*)(Bs + sr * 32 + sc)        = b0;
        *(bf16x8*)(Bs + (64 + sr) * 32 + sc) = b1;
        __syncthreads();

        bf16x8 af[4], bfr[4];
#pragma unroll
        for (int a = 0; a < 4; ++a)
            af[a] = *(const bf16x8*)(As + (wm * 64 + a * 16 + l) * 32 + quad * 8);
#pragma unroll
        for (int b = 0; b < 4; ++b)
            bfr[b] = *(const bf16x8*)(Bs + (wn * 64 + b * 16 + l) * 32 + quad * 8);
#pragma unroll
        for (int a = 0; a < 4; ++a)
#pragma unroll
            for (int b = 0; b < 4; ++b)
                acc[a][b] = tr ? MFMA16(bfr[b], af[a], acc[a][b])
                               : MFMA16(af[a], bfr[b], acc[a][b]);
    }

#pragma unroll
    for (int a = 0; a < 4; ++a)
#pragma unroll
        for (int b = 0; b < 4; ++b)
#pragma unroll
            for (int r = 0; r < 4; ++r) {
                float v = acc[a][b][r];
                if (mode == 3) {
                    const int m  = m0 + wm * 64 + a * 16 + quad * 4 + r;
                    const int nn = n0 + wn * 64 + b * 16 + l;
                    ((float*)out_v)[(size_t)m * DM + nn] = v;
                } else if (mode == 2) {
                    // transposed tile: row = n-dim, col = m-dim
                    const int n = n0 + wn * 64 + b * 16 + quad * 4 + r;
                    const int m = m0 + wm * 64 + a * 16 + l;
                    const int bi = m >> 11, s = m & (SEQ - 1);
                    const int h = n >> 6, d = n & (DK - 1);
                    ((bf16_t*)out_v)[(((size_t)(bi * NH + h)) * DK + d) * SEQ + s] = (bf16_t)v;
                } else {
                    const int m  = m0 + wm * 64 + a * 16 + quad * 4 + r;
                    const int nn = n0 + wn * 64 + b * 16 + l;
                    const int bi = m >> 11, s = m & (SEQ - 1);
                    const int h = nn >> 6, d = nn & (DK - 1);
                    float pv = __shfl_xor(v, 1);
                    float2 cs = rope[s * 32 + (d >> 1)];
                    float res = (d & 1) ? (v * cs.x + pv * cs.y)
                                        : (v * cs.x - pv * cs.y);
                    if (mode == 0) res *= 0.125f;   // fold 1/sqrt(dk) into Q
                    ((bf16_t*)out_v)[(((size_t)(bi * NH + h)) * SEQ + s) * DK + d] = (bf16_t)res;
                }
            }
}

// ---------------------------------------------------------------------------
// Causal flash attention, transposed-score layout.
// Qt,Kt: [B,H,S,dk] (Q pre-scaled by 1/8); Vt: [B,H,dk,S]; Ot: [B,S,D] bf16.
// Wave = 16 queries (query = lane&15 = C col). 64-key chunks.
// S^T = K·Q^T (per-lane: 16 key-scores of ONE query -> in-register softmax),
// O^T = V^T·P^T (per-lane alpha rescale, no broadcasts).
// ---------------------------------------------------------------------------
#define PLD 72   // LDS row stride (bf16): 144 B, 16B-aligned

__global__ __launch_bounds__(256) void attn_kernel(
    const bf16_t* __restrict__ Q, const bf16_t* __restrict__ K,
    const bf16_t* __restrict__ Vt, bf16_t* __restrict__ O)
{
    __shared__ __align__(16) bf16_t Pl[4][16 * PLD];

    const int bh   = blockIdx.y;
    const int wave = threadIdx.x >> 6;
    const int lane = threadIdx.x & 63;
    const int l    = lane & 15;
    const int quad = lane >> 4;
    const int q0   = blockIdx.x * 64 + wave * 16;

    bf16_t* P = Pl[wave];
    const bf16_t* Qb = Q  + (size_t)bh * SEQ * DK;
    const bf16_t* Kb = K  + (size_t)bh * SEQ * DK;
    const bf16_t* Vb = Vt + (size_t)bh * DK * SEQ;

    // Q as B-fragment of Q^T: lane l holds query q0+l, k = quad*8+j
    const bf16x8 qb0 = *(const bf16x8*)(Qb + (q0 + l) * DK + quad * 8);
    const bf16x8 qb1 = *(const bf16x8*)(Qb + (q0 + l) * DK + 32 + quad * 8);

    float m_run = -3e38f, l_run = 0.0f;
    f32x4 o[4] = {};   // O^T tiles: o[n][r] = O^T[d = n*16+quad*4+r][q = q0+l]

    for (int c = 0; c <= q0 + 15; c += 64) {
        // S^T tiles: st[t][r] = S(key = c+t*16+quad*4+r, query = q0+l)
        f32x4 st[4] = {};
#pragma unroll
        for (int t = 0; t < 4; ++t) {
            const bf16_t* kp = Kb + (c + t * 16 + l) * DK;
            bf16x8 kb0 = *(const bf16x8*)(kp + quad * 8);
            st[t] = MFMA16(kb0, qb0, st[t]);
            bf16x8 kb1 = *(const bf16x8*)(kp + 32 + quad * 8);
            st[t] = MFMA16(kb1, qb1, st[t]);
        }

        if (c + 63 > q0) {  // causal mask (tail chunk only)
            const int thr = q0 + l - c - quad * 4;  // mask if t*16 + r > thr
#pragma unroll
            for (int t = 0; t < 4; ++t)
#pragma unroll
                for (int r = 0; r < 4; ++r)
                    if (t * 16 + r > thr) st[t][r] = -3e38f;
        }

        // max over 16 in-register values + 2 cross-quad shuffles
        float m01 = fmaxf(fmaxf(st[0][0], st[0][1]), fmaxf(st[0][2], st[0][3]));
        float m23 = fmaxf(fmaxf(st[1][0], st[1][1]), fmaxf(st[1][2], st[1][3]));
        float m45 = fmaxf(fmaxf(st[2][0], st[2][1]), fmaxf(st[2][2], st[2][3]));
        float m67 = fmaxf(fmaxf(st[3][0], st[3][1]), fmaxf(st[3][2], st[3][3]));
        float cmax = fmaxf(fmaxf(m01, m23), fmaxf(m45, m67));
        cmax = fmaxf(cmax, __shfl_xor(cmax, 16));
        cmax = fmaxf(cmax, __shfl_xor(cmax, 32));

        const float mnew  = fmaxf(m_run, cmax);
        const float alpha = __expf(m_run - mnew);
        m_run = mnew;

#pragma unroll
        for (int t = 0; t < 4; ++t)
#pragma unroll
            for (int r = 0; r < 4; ++r)
                st[t][r] = __expf(st[t][r] - mnew);

        float s01 = (st[0][0] + st[0][1]) + (st[0][2] + st[0][3]);
        float s23 = (st[1][0] + st[1][1]) + (st[1][2] + st[1][3]);
        float s45 = (st[2][0] + st[2][1]) + (st[2][2] + st[2][3]);
        float s67 = (st[3][0] + st[3][1]) + (st[3][2] + st[3][3]);
        float csum = (s01 + s23) + (s45 + s67);
        csum += __shfl_xor(csum, 16);
        csum += __shfl_xor(csum, 32);
        l_run = l_run * alpha + csum;

#pragma unroll
        for (int n = 0; n < 4; ++n)
#pragma unroll
            for (int r = 0; r < 4; ++r)
                o[n][r] *= alpha;

        // P -> LDS [query][key] (b64 writes), read back as B-frags of P^T
#pragma unroll
        for (int t = 0; t < 4; ++t) {
            bf16x4 pk;
            pk[0] = (bf16_t)st[t][0]; pk[1] = (bf16_t)st[t][1];
            pk[2] = (bf16_t)st[t][2]; pk[3] = (bf16_t)st[t][3];
            *(bf16x4*)(P + l * PLD + t * 16 + quad * 4) = pk;
        }
        const bf16x8 pb0 = *(const bf16x8*)(P + l * PLD + quad * 8);
        const bf16x8 pb1 = *(const bf16x8*)(P + l * PLD + 32 + quad * 8);

#pragma unroll
        for (int n = 0; n < 4; ++n) {
            const bf16_t* vp = Vb + (size_t)(n * 16 + l) * SEQ + c;
            bf16x8 vb0 = *(const bf16x8*)(vp + quad * 8);
            o[n] = MFMA16(vb0, pb0, o[n]);
            bf16x8 vb1 = *(const bf16x8*)(vp + 32 + quad * 8);
            o[n] = MFMA16(vb1, pb1, o[n]);
        }
    }

    // epilogue: O^T -> LDS [query][d] -> coalesced row stores
    const float inv = 1.0f / l_run;
#pragma unroll
    for (int n = 0; n < 4; ++n) {
        bf16x4 ov;
        ov[0] = (bf16_t)(o[n][0] * inv); ov[1] = (bf16_t)(o[n][1] * inv);
        ov[2] = (bf16_t)(o[n][2] * inv); ov[3] = (bf16_t)(o[n][3] * inv);
        *(bf16x4*)(P + l * PLD + n * 16 + quad * 4) = ov;
    }
    const int row = lane >> 2, ch = lane & 3;
    bf16x8 w0 = *(const bf16x8*)(P + row * PLD + ch * 8);
    bf16x8 w1 = *(const bf16x8*)(P + row * PLD + 32 + ch * 8);
    const int b = bh >> 4, h = bh & 15;
    bf16_t* op = O + ((size_t)(b * SEQ + q0 + row)) * DM + h * DK;
    *(bf16x8*)(op + ch * 8)      = w0;
    *(bf16x8*)(op + 32 + ch * 8) = w1;
}

// ---------------------------------------------------------------------------
extern "C" void kernel_launch(void* const* d_in, const int* in_sizes, int n_in,
                              void* d_out, int out_size, void* d_ws, size_t ws_size,
                              hipStream_t stream)
{
    const float* x  = (const float*)d_in[0];
    const float* Wq = (const float*)d_in[1];
    const float* Wk = (const float*)d_in[2];
    const float* Wv = (const float*)d_in[3];
    const float* Wo = (const float*)d_in[4];

    char* ws = (char*)d_ws;
    float2* rope = (float2*)ws;                        // 512 KiB
    const size_t TEN = (size_t)MROWS * DM;             // 8,388,608 elems
    const size_t WEL = (size_t)DM * DM;                // 1,048,576 elems
    bf16_t* xb  = (bf16_t*)(ws + (1 << 19));
    bf16_t* Wqt = xb  + TEN;
    bf16_t* Wkt = Wqt + WEL;
    bf16_t* Wvt = Wkt + WEL;
    bf16_t* Wot = Wvt + WEL;
    bf16_t* Qt  = Wot + WEL;
    bf16_t* Kt  = Qt + TEN;
    bf16_t* Vt  = Kt + TEN;
    bf16_t* Ot  = Vt + TEN;                            // total ~88.5 MB

    rope_table_kernel<<<(SEQ * 32 + 255) / 256, 256, 0, stream>>>(rope);

    cvt_kernel<<<(int)(TEN / 4 / 256), 256, 0, stream>>>(x, xb, (int)TEN);
    wtr_kernel<<<1024, 256, 0, stream>>>(Wq, Wqt);
    wtr_kernel<<<1024, 256, 0, stream>>>(Wk, Wkt);
    wtr_kernel<<<1024, 256, 0, stream>>>(Wv, Wvt);
    wtr_kernel<<<1024, 256, 0, stream>>>(Wo, Wot);

    const int gemm_grid = (MROWS / 128) * (DM / 128);  // 64*8 = 512
    gemm_ep_kernel<<<gemm_grid, 256, 0, stream>>>(xb, Wqt, Qt, rope, 0);
    gemm_ep_kernel<<<gemm_grid, 256, 0, stream>>>(xb, Wkt, Kt, rope, 1);
    gemm_ep_kernel<<<gemm_grid, 256, 0, stream>>>(xb, Wvt, Vt, rope, 2);

    attn_kernel<<<dim3(SEQ / 64, NB * NH), 256, 0, stream>>>(Qt, Kt, Vt, Ot);

    gemm_ep_kernel<<<gemm_grid, 256, 0, stream>>>(Ot, Wot, d_out, rope, 3);
}

// Round 4
// 411.783 us; speedup vs baseline: 2.2502x; 1.9095x over previous
//
#include <hip/hip_runtime.h>
#include <hip/hip_bf16.h>

// Problem constants: B=4, S=2048, D=1024, H=16, dk=64
#define SEQ   2048
#define NB    4
#define NH    16
#define DK    64
#define DM    1024
#define MROWS (NB * SEQ)   // 8192

typedef __bf16 bf16_t;
typedef __bf16 bf16x8 __attribute__((ext_vector_type(8)));
typedef __bf16 bf16x4 __attribute__((ext_vector_type(4)));
typedef float  f32x4  __attribute__((ext_vector_type(4)));

#define MFMA16(a, b, c) __builtin_amdgcn_mfma_f32_16x16x32_bf16((a), (b), (c), 0, 0, 0)

// ---------------------------------------------------------------------------
// fp32 -> bf16 conversion (x)
// ---------------------------------------------------------------------------
__global__ __launch_bounds__(256) void cvt_kernel(
    const float* __restrict__ in, bf16_t* __restrict__ out, int n)
{
    int i = (blockIdx.x * 256 + threadIdx.x) * 4;
    if (i + 3 < n) {
        const float4 v = *(const float4*)(in + i);
        bf16x4 o;
        o[0] = (bf16_t)v.x; o[1] = (bf16_t)v.y;
        o[2] = (bf16_t)v.z; o[3] = (bf16_t)v.w;
        *(bf16x4*)(out + i) = o;
    }
}

// ---------------------------------------------------------------------------
// Weight transpose + cast: Wt[n][k] = (bf16)W[k][n].  32x32 tiles via LDS.
// ---------------------------------------------------------------------------
__global__ __launch_bounds__(256) void wtr_kernel(
    const float* __restrict__ W, bf16_t* __restrict__ Wt)
{
    __shared__ float T[32][33];
    const int tk0 = (blockIdx.x >> 5) << 5;
    const int tn0 = (blockIdx.x & 31) << 5;
    const int r = threadIdx.x >> 5, c = threadIdx.x & 31;
#pragma unroll
    for (int i = 0; i < 4; ++i)
        T[r + i * 8][c] = W[(size_t)(tk0 + r + i * 8) * DM + tn0 + c];
    __syncthreads();
#pragma unroll
    for (int i = 0; i < 4; ++i)
        Wt[(size_t)(tn0 + r + i * 8) * DM + tk0 + c] = (bf16_t)T[c][r + i * 8];
}

// ---------------------------------------------------------------------------
// RoPE table: tab[s*32+i] = (cos, sin) of s * 10000^(-i/32)
// ---------------------------------------------------------------------------
__global__ void rope_table_kernel(float2* __restrict__ tab) {
    int idx = blockIdx.x * 256 + threadIdx.x;
    if (idx >= SEQ * 32) return;
    int s = idx >> 5, i = idx & 31;
    float freq = powf(10000.0f, -(float)i / 32.0f);
    float a = (float)s * freq;
    tab[idx] = make_float2(cosf(a), sinf(a));
}

// ---------------------------------------------------------------------------
// GEMM: C = X(8192x1024) @ Wt^T, Wt stored [N][K] row-major (pre-transposed).
// 128x128x32 tile, 4 waves (2x2), each wave 4x4 16x16 tiles.
// mode 0: RoPE + 1/8 scale -> Qt [B,H,S,dk] bf16
// mode 1: RoPE            -> Kt [B,H,S,dk] bf16
// mode 2: transposed C (swap MFMA operands) -> Vt [B,H,dk,S] bf16
// mode 3: plain fp32 row-major -> d_out
// ---------------------------------------------------------------------------
__global__ __launch_bounds__(256) void gemm_ep_kernel(
    const bf16_t* __restrict__ X, const bf16_t* __restrict__ Wt,
    void* __restrict__ out_v, const float2* __restrict__ rope, int mode)
{
    __shared__ __align__(16) bf16_t As[128 * 32];
    __shared__ __align__(16) bf16_t Bs[128 * 32];

    const int tid  = threadIdx.x;
    const int lane = tid & 63;
    const int wave = tid >> 6;
    const int wm   = wave & 1, wn = wave >> 1;
    const int l    = lane & 15;
    const int quad = lane >> 4;

    const int m0 = (blockIdx.x >> 3) << 7;
    const int n0 = (blockIdx.x & 7) << 7;

    const int sr = tid >> 2;          // 0..63
    const int sc = (tid & 3) << 3;    // 0,8,16,24

    f32x4 acc[4][4] = {};
    const bool tr = (mode == 2);

    for (int k0 = 0; k0 < DM; k0 += 32) {
        bf16x8 a0 = *(const bf16x8*)(X  + (size_t)(m0 + sr) * DM + k0 + sc);
        bf16x8 a1 = *(const bf16x8*)(X  + (size_t)(m0 + 64 + sr) * DM + k0 + sc);
        bf16x8 b0 = *(const bf16x8*)(Wt + (size_t)(n0 + sr) * DM + k0 + sc);
        bf16x8 b1 = *(const bf16x8*)(Wt + (size_t)(n0 + 64 + sr) * DM + k0 + sc);
        __syncthreads();
        *(bf16x8*)(As + sr * 32 + sc)        = a0;
        *(bf16x8*)(As + (64 + sr) * 32 + sc) = a1;
        *(bf16x8*)(Bs + sr * 32 + sc)        = b0;
        *(bf16x8*)(Bs + (64 + sr) * 32 + sc) = b1;
        __syncthreads();

        bf16x8 af[4], bfr[4];
#pragma unroll
        for (int a = 0; a < 4; ++a)
            af[a] = *(const bf16x8*)(As + (wm * 64 + a * 16 + l) * 32 + quad * 8);
#pragma unroll
        for (int b = 0; b < 4; ++b)
            bfr[b] = *(const bf16x8*)(Bs + (wn * 64 + b * 16 + l) * 32 + quad * 8);
#pragma unroll
        for (int a = 0; a < 4; ++a)
#pragma unroll
            for (int b = 0; b < 4; ++b)
                acc[a][b] = tr ? MFMA16(bfr[b], af[a], acc[a][b])
                               : MFMA16(af[a], bfr[b], acc[a][b]);
    }

#pragma unroll
    for (int a = 0; a < 4; ++a)
#pragma unroll
        for (int b = 0; b < 4; ++b)
#pragma unroll
            for (int r = 0; r < 4; ++r) {
                float v = acc[a][b][r];
                if (mode == 3) {
                    const int m  = m0 + wm * 64 + a * 16 + quad * 4 + r;
                    const int nn = n0 + wn * 64 + b * 16 + l;
                    ((float*)out_v)[(size_t)m * DM + nn] = v;
                } else if (mode == 2) {
                    const int n = n0 + wn * 64 + b * 16 + quad * 4 + r;
                    const int m = m0 + wm * 64 + a * 16 + l;
                    const int bi = m >> 11, s = m & (SEQ - 1);
                    const int h = n >> 6, d = n & (DK - 1);
                    ((bf16_t*)out_v)[(((size_t)(bi * NH + h)) * DK + d) * SEQ + s] = (bf16_t)v;
                } else {
                    const int m  = m0 + wm * 64 + a * 16 + quad * 4 + r;
                    const int nn = n0 + wn * 64 + b * 16 + l;
                    const int bi = m >> 11, s = m & (SEQ - 1);
                    const int h = nn >> 6, d = nn & (DK - 1);
                    float pv = __shfl_xor(v, 1);
                    float2 cs = rope[s * 32 + (d >> 1)];
                    float res = (d & 1) ? (v * cs.x + pv * cs.y)
                                        : (v * cs.x - pv * cs.y);
                    if (mode == 0) res *= 0.125f;
                    ((bf16_t*)out_v)[(((size_t)(bi * NH + h)) * SEQ + s) * DK + d] = (bf16_t)res;
                }
            }
}

// ---------------------------------------------------------------------------
// Causal flash attention, balanced + LDS-shared + pipelined.
// Qt,Kt: [B,H,S,dk] (Q pre-scaled 1/8); Vt: [B,H,dk,S]; Ot: [B,S,D] bf16.
// Block (4 waves) processes query-block pair (J, 15-J), 128 queries each;
// every block does exactly 34 key-chunks of 64 -> perfect balance.
// Wave = 32 queries (u=0,1 tiles of 16). K/V chunk staged in LDS (shared by
// all waves), prefetched into VGPRs one chunk ahead.
// ---------------------------------------------------------------------------
#define KLD 72   // LDS row stride (elems): 144 B

__global__ __launch_bounds__(256) void attn_kernel(
    const bf16_t* __restrict__ Q, const bf16_t* __restrict__ K,
    const bf16_t* __restrict__ Vt, bf16_t* __restrict__ O)
{
    __shared__ __align__(16) bf16_t Kl[64 * KLD];
    __shared__ __align__(16) bf16_t Vl[64 * KLD];
    __shared__ __align__(16) bf16_t Pl[4][32 * KLD];

    const int bh   = blockIdx.y;
    const int tid  = threadIdx.x;
    const int wave = tid >> 6;
    const int lane = tid & 63;
    const int l    = lane & 15;
    const int quad = lane >> 4;
    const int srow = tid >> 3;        // 0..31 (staging row)
    const int sch  = (tid & 7) << 3;  // staging col elem offset

    bf16_t* Pw = Pl[wave];
    const bf16_t* Qb = Q  + (size_t)bh * SEQ * DK;
    const bf16_t* Kb = K  + (size_t)bh * SEQ * DK;
    const bf16_t* Vb = Vt + (size_t)bh * DK * SEQ;
    const int b = bh >> 4, h = bh & 15;

    for (int ph = 0; ph < 2; ++ph) {
        const int qblk = ph ? (15 - (int)blockIdx.x) : (int)blockIdx.x;
        const int q0w  = qblk * 128 + wave * 32;
        const int nch  = 2 * (qblk + 1);

        // Q fragments (persistent for the phase)
        bf16x8 qb[2][2];
#pragma unroll
        for (int u = 0; u < 2; ++u) {
            qb[u][0] = *(const bf16x8*)(Qb + (size_t)(q0w + u * 16 + l) * DK + quad * 8);
            qb[u][1] = *(const bf16x8*)(Qb + (size_t)(q0w + u * 16 + l) * DK + 32 + quad * 8);
        }

        float m_run[2] = {-3e38f, -3e38f};
        float l_run[2] = {0.f, 0.f};
        f32x4 o[4][2] = {};

        // prefetch chunk 0
        bf16x8 pk0 = *(const bf16x8*)(Kb + (size_t)srow * DK + sch);
        bf16x8 pk1 = *(const bf16x8*)(Kb + (size_t)(32 + srow) * DK + sch);
        bf16x8 pv0 = *(const bf16x8*)(Vb + (size_t)srow * SEQ + sch);
        bf16x8 pv1 = *(const bf16x8*)(Vb + (size_t)(32 + srow) * SEQ + sch);

        for (int i = 0; i < nch; ++i) {
            const int c = i * 64;
            __syncthreads();
            *(bf16x8*)(Kl + srow * KLD + sch)        = pk0;
            *(bf16x8*)(Kl + (32 + srow) * KLD + sch) = pk1;
            *(bf16x8*)(Vl + srow * KLD + sch)        = pv0;
            *(bf16x8*)(Vl + (32 + srow) * KLD + sch) = pv1;
            __syncthreads();
            if (i + 1 < nch) {  // prefetch next chunk (overlaps compute)
                const int cn = c + 64;
                pk0 = *(const bf16x8*)(Kb + (size_t)(cn + srow) * DK + sch);
                pk1 = *(const bf16x8*)(Kb + (size_t)(cn + 32 + srow) * DK + sch);
                pv0 = *(const bf16x8*)(Vb + (size_t)srow * SEQ + cn + sch);
                pv1 = *(const bf16x8*)(Vb + (size_t)(32 + srow) * SEQ + cn + sch);
            }
            if (c > q0w + 31) continue;   // fully masked for this wave

            // --- QK^T (S^T layout: key=M, query=N) ---
            f32x4 st[4][2] = {};
#pragma unroll
            for (int t = 0; t < 4; ++t) {
                const bf16x8 k0 = *(const bf16x8*)(Kl + (t * 16 + l) * KLD + quad * 8);
                const bf16x8 k1 = *(const bf16x8*)(Kl + (t * 16 + l) * KLD + 32 + quad * 8);
                st[t][0] = MFMA16(k0, qb[0][0], st[t][0]);
                st[t][0] = MFMA16(k1, qb[0][1], st[t][0]);
                st[t][1] = MFMA16(k0, qb[1][0], st[t][1]);
                st[t][1] = MFMA16(k1, qb[1][1], st[t][1]);
            }
            if (c + 63 > q0w) {  // causal mask
#pragma unroll
                for (int u = 0; u < 2; ++u) {
                    const int thr = q0w + u * 16 + l - c - quad * 4;
#pragma unroll
                    for (int t = 0; t < 4; ++t)
#pragma unroll
                        for (int r = 0; r < 4; ++r)
                            if (t * 16 + r > thr) st[t][u][r] = -3e38f;
                }
            }
            // --- online softmax (per-lane: 16 scores of one query per u) ---
#pragma unroll
            for (int u = 0; u < 2; ++u) {
                float cmax = -3e38f;
#pragma unroll
                for (int t = 0; t < 4; ++t)
#pragma unroll
                    for (int r = 0; r < 4; ++r)
                        cmax = fmaxf(cmax, st[t][u][r]);
                cmax = fmaxf(cmax, __shfl_xor(cmax, 16));
                cmax = fmaxf(cmax, __shfl_xor(cmax, 32));
                const float mnew  = fmaxf(m_run[u], cmax);
                const float alpha = __expf(m_run[u] - mnew);
                m_run[u] = mnew;
                float csum = 0.f;
#pragma unroll
                for (int t = 0; t < 4; ++t)
#pragma unroll
                    for (int r = 0; r < 4; ++r) {
                        st[t][u][r] = __expf(st[t][u][r] - mnew);
                        csum += st[t][u][r];
                    }
                csum += __shfl_xor(csum, 16);
                csum += __shfl_xor(csum, 32);
                l_run[u] = l_run[u] * alpha + csum;
#pragma unroll
                for (int n = 0; n < 4; ++n)
#pragma unroll
                    for (int r = 0; r < 4; ++r)
                        o[n][u][r] *= alpha;
                // P -> LDS [query][key]
#pragma unroll
                for (int t = 0; t < 4; ++t) {
                    bf16x4 pk;
                    pk[0] = (bf16_t)st[t][u][0]; pk[1] = (bf16_t)st[t][u][1];
                    pk[2] = (bf16_t)st[t][u][2]; pk[3] = (bf16_t)st[t][u][3];
                    *(bf16x4*)(Pw + (u * 16 + l) * KLD + t * 16 + quad * 4) = pk;
                }
            }
            // --- PV: O^T += V^T · P^T (same-wave LDS ordering) ---
            const bf16x8 pb00 = *(const bf16x8*)(Pw + l * KLD + quad * 8);
            const bf16x8 pb01 = *(const bf16x8*)(Pw + l * KLD + 32 + quad * 8);
            const bf16x8 pb10 = *(const bf16x8*)(Pw + (16 + l) * KLD + quad * 8);
            const bf16x8 pb11 = *(const bf16x8*)(Pw + (16 + l) * KLD + 32 + quad * 8);
#pragma unroll
            for (int n = 0; n < 4; ++n) {
                const bf16x8 v0 = *(const bf16x8*)(Vl + (n * 16 + l) * KLD + quad * 8);
                const bf16x8 v1 = *(const bf16x8*)(Vl + (n * 16 + l) * KLD + 32 + quad * 8);
                o[n][0] = MFMA16(v0, pb00, o[n][0]);
                o[n][0] = MFMA16(v1, pb01, o[n][0]);
                o[n][1] = MFMA16(v0, pb10, o[n][1]);
                o[n][1] = MFMA16(v1, pb11, o[n][1]);
            }
        }

        // --- epilogue: normalize, transpose via own P region, store ---
#pragma unroll
        for (int u = 0; u < 2; ++u) {
            const float inv = 1.0f / l_run[u];
#pragma unroll
            for (int n = 0; n < 4; ++n) {
                bf16x4 ov;
                ov[0] = (bf16_t)(o[n][u][0] * inv); ov[1] = (bf16_t)(o[n][u][1] * inv);
                ov[2] = (bf16_t)(o[n][u][2] * inv); ov[3] = (bf16_t)(o[n][u][3] * inv);
                *(bf16x4*)(Pw + (u * 16 + l) * KLD + n * 16 + quad * 4) = ov;
            }
        }
        const int row  = lane >> 1;          // 0..31
        const int half = (lane & 1) * 32;    // elem offset
        const bf16x8 w0 = *(const bf16x8*)(Pw + row * KLD + half);
        const bf16x8 w1 = *(const bf16x8*)(Pw + row * KLD + half + 8);
        const bf16x8 w2 = *(const bf16x8*)(Pw + row * KLD + half + 16);
        const bf16x8 w3 = *(const bf16x8*)(Pw + row * KLD + half + 24);
        bf16_t* op = O + ((size_t)(b * SEQ + qblk * 128 + wave * 32 + row)) * DM
                       + h * DK + half;
        *(bf16x8*)(op)      = w0;
        *(bf16x8*)(op + 8)  = w1;
        *(bf16x8*)(op + 16) = w2;
        *(bf16x8*)(op + 24) = w3;
    }
}

// ---------------------------------------------------------------------------
extern "C" void kernel_launch(void* const* d_in, const int* in_sizes, int n_in,
                              void* d_out, int out_size, void* d_ws, size_t ws_size,
                              hipStream_t stream)
{
    const float* x  = (const float*)d_in[0];
    const float* Wq = (const float*)d_in[1];
    const float* Wk = (const float*)d_in[2];
    const float* Wv = (const float*)d_in[3];
    const float* Wo = (const float*)d_in[4];

    char* ws = (char*)d_ws;
    float2* rope = (float2*)ws;                        // 512 KiB
    const size_t TEN = (size_t)MROWS * DM;
    const size_t WEL = (size_t)DM * DM;
    bf16_t* xb  = (bf16_t*)(ws + (1 << 19));
    bf16_t* Wqt = xb  + TEN;
    bf16_t* Wkt = Wqt + WEL;
    bf16_t* Wvt = Wkt + WEL;
    bf16_t* Wot = Wvt + WEL;
    bf16_t* Qt  = Wot + WEL;
    bf16_t* Kt  = Qt + TEN;
    bf16_t* Vt  = Kt + TEN;
    bf16_t* Ot  = Vt + TEN;

    rope_table_kernel<<<(SEQ * 32 + 255) / 256, 256, 0, stream>>>(rope);

    cvt_kernel<<<(int)(TEN / 4 / 256), 256, 0, stream>>>(x, xb, (int)TEN);
    wtr_kernel<<<1024, 256, 0, stream>>>(Wq, Wqt);
    wtr_kernel<<<1024, 256, 0, stream>>>(Wk, Wkt);
    wtr_kernel<<<1024, 256, 0, stream>>>(Wv, Wvt);
    wtr_kernel<<<1024, 256, 0, stream>>>(Wo, Wot);

    const int gemm_grid = (MROWS / 128) * (DM / 128);  // 512
    gemm_ep_kernel<<<gemm_grid, 256, 0, stream>>>(xb, Wqt, Qt, rope, 0);
    gemm_ep_kernel<<<gemm_grid, 256, 0, stream>>>(xb, Wkt, Kt, rope, 1);
    gemm_ep_kernel<<<gemm_grid, 256, 0, stream>>>(xb, Wvt, Vt, rope, 2);

    // pair-balanced causal attention: 8 pair-blocks x 64 (b,h)
    attn_kernel<<<dim3(8, NB * NH), 256, 0, stream>>>(Qt, Kt, Vt, Ot);

    gemm_ep_kernel<<<gemm_grid, 256, 0, stream>>>(Ot, Wot, d_out, rope, 3);
}

// Round 5
// 392.505 us; speedup vs baseline: 2.3607x; 1.0491x over previous
//
#include <hip/hip_runtime.h>
#include <hip/hip_bf16.h>

// Problem constants: B=4, S=2048, D=1024, H=16, dk=64
#define SEQ   2048
#define NB    4
#define NH    16
#define DK    64
#define DM    1024
#define MROWS (NB * SEQ)   // 8192

typedef __bf16 bf16_t;
typedef __bf16 bf16x8 __attribute__((ext_vector_type(8)));
typedef __bf16 bf16x4 __attribute__((ext_vector_type(4)));
typedef float  f32x4  __attribute__((ext_vector_type(4)));

#define MFMA16(a, b, c) __builtin_amdgcn_mfma_f32_16x16x32_bf16((a), (b), (c), 0, 0, 0)

// async global->LDS, 16B per lane. LDS dest must be wave-uniform base;
// HW scatters to base + lane*16.
__device__ __forceinline__ void gl2lds16(const bf16_t* g, bf16_t* l) {
    __builtin_amdgcn_global_load_lds(
        (const __attribute__((address_space(1))) unsigned int*)g,
        (__attribute__((address_space(3))) unsigned int*)l, 16, 0, 0);
}

// ---------------------------------------------------------------------------
// fp32 -> bf16 conversion (x)
// ---------------------------------------------------------------------------
__global__ __launch_bounds__(256) void cvt_kernel(
    const float* __restrict__ in, bf16_t* __restrict__ out, int n)
{
    int i = (blockIdx.x * 256 + threadIdx.x) * 4;
    if (i + 3 < n) {
        const float4 v = *(const float4*)(in + i);
        bf16x4 o;
        o[0] = (bf16_t)v.x; o[1] = (bf16_t)v.y;
        o[2] = (bf16_t)v.z; o[3] = (bf16_t)v.w;
        *(bf16x4*)(out + i) = o;
    }
}

// ---------------------------------------------------------------------------
// Weight transpose + cast: Wt[n][k] = (bf16)W[k][n].  32x32 tiles via LDS.
// ---------------------------------------------------------------------------
__global__ __launch_bounds__(256) void wtr_kernel(
    const float* __restrict__ W, bf16_t* __restrict__ Wt)
{
    __shared__ float T[32][33];
    const int tk0 = (blockIdx.x >> 5) << 5;
    const int tn0 = (blockIdx.x & 31) << 5;
    const int r = threadIdx.x >> 5, c = threadIdx.x & 31;
#pragma unroll
    for (int i = 0; i < 4; ++i)
        T[r + i * 8][c] = W[(size_t)(tk0 + r + i * 8) * DM + tn0 + c];
    __syncthreads();
#pragma unroll
    for (int i = 0; i < 4; ++i)
        Wt[(size_t)(tn0 + r + i * 8) * DM + tk0 + c] = (bf16_t)T[c][r + i * 8];
}

// ---------------------------------------------------------------------------
// RoPE table: tab[s*32+i] = (cos, sin) of s * 10000^(-i/32)
// ---------------------------------------------------------------------------
__global__ void rope_table_kernel(float2* __restrict__ tab) {
    int idx = blockIdx.x * 256 + threadIdx.x;
    if (idx >= SEQ * 32) return;
    int s = idx >> 5, i = idx & 31;
    float freq = powf(10000.0f, -(float)i / 32.0f);
    float a = (float)s * freq;
    tab[idx] = make_float2(cosf(a), sinf(a));
}

// ---------------------------------------------------------------------------
// Merged QKV GEMM: C = X(8192x1024) @ Wqkv^T, Wqkv stored [3072][1024].
// 128x128x(BK=64) tile, global_load_lds staging in fragment-order groups:
//   group g = nt*2+kc (1 KB): lane i <-> (row nt*16+(i&15), k kc*32+(i>>4)*8)
// Epilogue by n0: n<1024 Q (RoPE*1/8), n<2048 K (RoPE), else V (transposed).
// ---------------------------------------------------------------------------
__global__ __launch_bounds__(256) void gemm_qkv_kernel(
    const bf16_t* __restrict__ X, const bf16_t* __restrict__ Wt,
    bf16_t* __restrict__ Qt, bf16_t* __restrict__ Kt, bf16_t* __restrict__ Vtr,
    const float2* __restrict__ rope)
{
    __shared__ __align__(16) bf16_t As[128 * 64];
    __shared__ __align__(16) bf16_t Bs[128 * 64];

    const int tid  = threadIdx.x;
    const int lane = tid & 63;
    const int wave = tid >> 6;
    const int wm   = wave & 1, wn = wave >> 1;
    const int l    = lane & 15;
    const int quad = lane >> 4;

    const int m0 = (blockIdx.x / 24) << 7;
    const int n0 = (blockIdx.x % 24) << 7;
    const bool tr = (n0 >= 2 * DM);   // V range

    const int rl = lane & 15;         // staging row-in-tile
    const int kf = (lane >> 4) << 3;  // staging k offset (elems)

    f32x4 acc[4][4] = {};

    for (int k0 = 0; k0 < DM; k0 += 64) {
#pragma unroll
        for (int g4 = 0; g4 < 4; ++g4) {
            const int g  = wave * 4 + g4;
            const int kc = g & 1, mt = g >> 1;
            gl2lds16(X  + (size_t)(m0 + mt * 16 + rl) * DM + k0 + kc * 32 + kf,
                     As + g * 512);
            gl2lds16(Wt + (size_t)(n0 + mt * 16 + rl) * DM + k0 + kc * 32 + kf,
                     Bs + g * 512);
        }
        __syncthreads();   // drains vmcnt: LDS data ready

        bf16x8 af[2][4], bw[2][4];
#pragma unroll
        for (int kc = 0; kc < 2; ++kc)
#pragma unroll
            for (int a = 0; a < 4; ++a) {
                af[kc][a] = *(const bf16x8*)(As + ((wm * 4 + a) * 2 + kc) * 512 + (quad * 16 + l) * 8);
                bw[kc][a] = *(const bf16x8*)(Bs + ((wn * 4 + a) * 2 + kc) * 512 + (quad * 16 + l) * 8);
            }
#pragma unroll
        for (int kc = 0; kc < 2; ++kc)
#pragma unroll
            for (int a = 0; a < 4; ++a)
#pragma unroll
                for (int b = 0; b < 4; ++b)
                    acc[a][b] = tr ? MFMA16(bw[kc][b], af[kc][a], acc[a][b])
                                   : MFMA16(af[kc][a], bw[kc][b], acc[a][b]);
        __syncthreads();   // all waves done reading before next stage
    }

#pragma unroll
    for (int a = 0; a < 4; ++a)
#pragma unroll
        for (int b = 0; b < 4; ++b)
#pragma unroll
            for (int r = 0; r < 4; ++r) {
                float v = acc[a][b][r];
                if (tr) {
                    const int n = n0 + wn * 64 + b * 16 + quad * 4 + r;
                    const int m = m0 + wm * 64 + a * 16 + l;
                    const int bi = m >> 11, s = m & (SEQ - 1);
                    const int col = n & (DM - 1);
                    const int h = col >> 6, d = col & (DK - 1);
                    Vtr[(((size_t)(bi * NH + h)) * DK + d) * SEQ + s] = (bf16_t)v;
                } else {
                    const int m  = m0 + wm * 64 + a * 16 + quad * 4 + r;
                    const int nn = n0 + wn * 64 + b * 16 + l;
                    const int bi = m >> 11, s = m & (SEQ - 1);
                    const int col = nn & (DM - 1);
                    const int h = col >> 6, d = col & (DK - 1);
                    float pv = __shfl_xor(v, 1);
                    float2 cs = rope[s * 32 + (d >> 1)];
                    float res = (d & 1) ? (v * cs.x + pv * cs.y)
                                        : (v * cs.x - pv * cs.y);
                    bf16_t* dst = (nn < DM) ? Qt : Kt;
                    if (nn < DM) res *= 0.125f;   // fold 1/sqrt(dk) into Q
                    dst[(((size_t)(bi * NH + h)) * SEQ + s) * DK + d] = (bf16_t)res;
                }
            }
}

// ---------------------------------------------------------------------------
// Output projection GEMM: d_out(fp32) = Ot(8192x1024,bf16) @ Wot^T.
// Same structure as gemm_qkv, N=1024, plain fp32 store.
// ---------------------------------------------------------------------------
__global__ __launch_bounds__(256) void gemm_out_kernel(
    const bf16_t* __restrict__ X, const bf16_t* __restrict__ Wt,
    float* __restrict__ out)
{
    __shared__ __align__(16) bf16_t As[128 * 64];
    __shared__ __align__(16) bf16_t Bs[128 * 64];

    const int tid  = threadIdx.x;
    const int lane = tid & 63;
    const int wave = tid >> 6;
    const int wm   = wave & 1, wn = wave >> 1;
    const int l    = lane & 15;
    const int quad = lane >> 4;

    const int m0 = (blockIdx.x >> 3) << 7;
    const int n0 = (blockIdx.x & 7) << 7;

    const int rl = lane & 15;
    const int kf = (lane >> 4) << 3;

    f32x4 acc[4][4] = {};

    for (int k0 = 0; k0 < DM; k0 += 64) {
#pragma unroll
        for (int g4 = 0; g4 < 4; ++g4) {
            const int g  = wave * 4 + g4;
            const int kc = g & 1, mt = g >> 1;
            gl2lds16(X  + (size_t)(m0 + mt * 16 + rl) * DM + k0 + kc * 32 + kf,
                     As + g * 512);
            gl2lds16(Wt + (size_t)(n0 + mt * 16 + rl) * DM + k0 + kc * 32 + kf,
                     Bs + g * 512);
        }
        __syncthreads();

        bf16x8 af[2][4], bw[2][4];
#pragma unroll
        for (int kc = 0; kc < 2; ++kc)
#pragma unroll
            for (int a = 0; a < 4; ++a) {
                af[kc][a] = *(const bf16x8*)(As + ((wm * 4 + a) * 2 + kc) * 512 + (quad * 16 + l) * 8);
                bw[kc][a] = *(const bf16x8*)(Bs + ((wn * 4 + a) * 2 + kc) * 512 + (quad * 16 + l) * 8);
            }
#pragma unroll
        for (int kc = 0; kc < 2; ++kc)
#pragma unroll
            for (int a = 0; a < 4; ++a)
#pragma unroll
                for (int b = 0; b < 4; ++b)
                    acc[a][b] = MFMA16(af[kc][a], bw[kc][b], acc[a][b]);
        __syncthreads();
    }

#pragma unroll
    for (int a = 0; a < 4; ++a)
#pragma unroll
        for (int b = 0; b < 4; ++b)
#pragma unroll
            for (int r = 0; r < 4; ++r) {
                const int m  = m0 + wm * 64 + a * 16 + quad * 4 + r;
                const int nn = n0 + wn * 64 + b * 16 + l;
                out[(size_t)m * DM + nn] = acc[a][b][r];
            }
}

// ---------------------------------------------------------------------------
// Causal flash attention (unchanged from round 4).
// ---------------------------------------------------------------------------
#define KLD 72   // LDS row stride (elems): 144 B

__global__ __launch_bounds__(256) void attn_kernel(
    const bf16_t* __restrict__ Q, const bf16_t* __restrict__ K,
    const bf16_t* __restrict__ Vt, bf16_t* __restrict__ O)
{
    __shared__ __align__(16) bf16_t Kl[64 * KLD];
    __shared__ __align__(16) bf16_t Vl[64 * KLD];
    __shared__ __align__(16) bf16_t Pl[4][32 * KLD];

    const int bh   = blockIdx.y;
    const int tid  = threadIdx.x;
    const int wave = tid >> 6;
    const int lane = tid & 63;
    const int l    = lane & 15;
    const int quad = lane >> 4;
    const int srow = tid >> 3;
    const int sch  = (tid & 7) << 3;

    bf16_t* Pw = Pl[wave];
    const bf16_t* Qb = Q  + (size_t)bh * SEQ * DK;
    const bf16_t* Kb = K  + (size_t)bh * SEQ * DK;
    const bf16_t* Vb = Vt + (size_t)bh * DK * SEQ;
    const int b = bh >> 4, h = bh & 15;

    for (int ph = 0; ph < 2; ++ph) {
        const int qblk = ph ? (15 - (int)blockIdx.x) : (int)blockIdx.x;
        const int q0w  = qblk * 128 + wave * 32;
        const int nch  = 2 * (qblk + 1);

        bf16x8 qb[2][2];
#pragma unroll
        for (int u = 0; u < 2; ++u) {
            qb[u][0] = *(const bf16x8*)(Qb + (size_t)(q0w + u * 16 + l) * DK + quad * 8);
            qb[u][1] = *(const bf16x8*)(Qb + (size_t)(q0w + u * 16 + l) * DK + 32 + quad * 8);
        }

        float m_run[2] = {-3e38f, -3e38f};
        float l_run[2] = {0.f, 0.f};
        f32x4 o[4][2] = {};

        bf16x8 pk0 = *(const bf16x8*)(Kb + (size_t)srow * DK + sch);
        bf16x8 pk1 = *(const bf16x8*)(Kb + (size_t)(32 + srow) * DK + sch);
        bf16x8 pv0 = *(const bf16x8*)(Vb + (size_t)srow * SEQ + sch);
        bf16x8 pv1 = *(const bf16x8*)(Vb + (size_t)(32 + srow) * SEQ + sch);

        for (int i = 0; i < nch; ++i) {
            const int c = i * 64;
            __syncthreads();
            *(bf16x8*)(Kl + srow * KLD + sch)        = pk0;
            *(bf16x8*)(Kl + (32 + srow) * KLD + sch) = pk1;
            *(bf16x8*)(Vl + srow * KLD + sch)        = pv0;
            *(bf16x8*)(Vl + (32 + srow) * KLD + sch) = pv1;
            __syncthreads();
            if (i + 1 < nch) {
                const int cn = c + 64;
                pk0 = *(const bf16x8*)(Kb + (size_t)(cn + srow) * DK + sch);
                pk1 = *(const bf16x8*)(Kb + (size_t)(cn + 32 + srow) * DK + sch);
                pv0 = *(const bf16x8*)(Vb + (size_t)srow * SEQ + cn + sch);
                pv1 = *(const bf16x8*)(Vb + (size_t)(32 + srow) * SEQ + cn + sch);
            }
            if (c > q0w + 31) continue;

            f32x4 st[4][2] = {};
#pragma unroll
            for (int t = 0; t < 4; ++t) {
                const bf16x8 k0 = *(const bf16x8*)(Kl + (t * 16 + l) * KLD + quad * 8);
                const bf16x8 k1 = *(const bf16x8*)(Kl + (t * 16 + l) * KLD + 32 + quad * 8);
                st[t][0] = MFMA16(k0, qb[0][0], st[t][0]);
                st[t][0] = MFMA16(k1, qb[0][1], st[t][0]);
                st[t][1] = MFMA16(k0, qb[1][0], st[t][1]);
                st[t][1] = MFMA16(k1, qb[1][1], st[t][1]);
            }
            if (c + 63 > q0w) {
#pragma unroll
                for (int u = 0; u < 2; ++u) {
                    const int thr = q0w + u * 16 + l - c - quad * 4;
#pragma unroll
                    for (int t = 0; t < 4; ++t)
#pragma unroll
                        for (int r = 0; r < 4; ++r)
                            if (t * 16 + r > thr) st[t][u][r] = -3e38f;
                }
            }
#pragma unroll
            for (int u = 0; u < 2; ++u) {
                float cmax = -3e38f;
#pragma unroll
                for (int t = 0; t < 4; ++t)
#pragma unroll
                    for (int r = 0; r < 4; ++r)
                        cmax = fmaxf(cmax, st[t][u][r]);
                cmax = fmaxf(cmax, __shfl_xor(cmax, 16));
                cmax = fmaxf(cmax, __shfl_xor(cmax, 32));
                const float mnew  = fmaxf(m_run[u], cmax);
                const float alpha = __expf(m_run[u] - mnew);
                m_run[u] = mnew;
                float csum = 0.f;
#pragma unroll
                for (int t = 0; t < 4; ++t)
#pragma unroll
                    for (int r = 0; r < 4; ++r) {
                        st[t][u][r] = __expf(st[t][u][r] - mnew);
                        csum += st[t][u][r];
                    }
                csum += __shfl_xor(csum, 16);
                csum += __shfl_xor(csum, 32);
                l_run[u] = l_run[u] * alpha + csum;
#pragma unroll
                for (int n = 0; n < 4; ++n)
#pragma unroll
                    for (int r = 0; r < 4; ++r)
                        o[n][u][r] *= alpha;
#pragma unroll
                for (int t = 0; t < 4; ++t) {
                    bf16x4 pk;
                    pk[0] = (bf16_t)st[t][u][0]; pk[1] = (bf16_t)st[t][u][1];
                    pk[2] = (bf16_t)st[t][u][2]; pk[3] = (bf16_t)st[t][u][3];
                    *(bf16x4*)(Pw + (u * 16 + l) * KLD + t * 16 + quad * 4) = pk;
                }
            }
            const bf16x8 pb00 = *(const bf16x8*)(Pw + l * KLD + quad * 8);
            const bf16x8 pb01 = *(const bf16x8*)(Pw + l * KLD + 32 + quad * 8);
            const bf16x8 pb10 = *(const bf16x8*)(Pw + (16 + l) * KLD + quad * 8);
            const bf16x8 pb11 = *(const bf16x8*)(Pw + (16 + l) * KLD + 32 + quad * 8);
#pragma unroll
            for (int n = 0; n < 4; ++n) {
                const bf16x8 v0 = *(const bf16x8*)(Vl + (n * 16 + l) * KLD + quad * 8);
                const bf16x8 v1 = *(const bf16x8*)(Vl + (n * 16 + l) * KLD + 32 + quad * 8);
                o[n][0] = MFMA16(v0, pb00, o[n][0]);
                o[n][0] = MFMA16(v1, pb01, o[n][0]);
                o[n][1] = MFMA16(v0, pb10, o[n][1]);
                o[n][1] = MFMA16(v1, pb11, o[n][1]);
            }
        }

#pragma unroll
        for (int u = 0; u < 2; ++u) {
            const float inv = 1.0f / l_run[u];
#pragma unroll
            for (int n = 0; n < 4; ++n) {
                bf16x4 ov;
                ov[0] = (bf16_t)(o[n][u][0] * inv); ov[1] = (bf16_t)(o[n][u][1] * inv);
                ov[2] = (bf16_t)(o[n][u][2] * inv); ov[3] = (bf16_t)(o[n][u][3] * inv);
                *(bf16x4*)(Pw + (u * 16 + l) * KLD + n * 16 + quad * 4) = ov;
            }
        }
        const int row  = lane >> 1;
        const int half = (lane & 1) * 32;
        const bf16x8 w0 = *(const bf16x8*)(Pw + row * KLD + half);
        const bf16x8 w1 = *(const bf16x8*)(Pw + row * KLD + half + 8);
        const bf16x8 w2 = *(const bf16x8*)(Pw + row * KLD + half + 16);
        const bf16x8 w3 = *(const bf16x8*)(Pw + row * KLD + half + 24);
        bf16_t* op = O + ((size_t)(b * SEQ + qblk * 128 + wave * 32 + row)) * DM
                       + h * DK + half;
        *(bf16x8*)(op)      = w0;
        *(bf16x8*)(op + 8)  = w1;
        *(bf16x8*)(op + 16) = w2;
        *(bf16x8*)(op + 24) = w3;
    }
}

// ---------------------------------------------------------------------------
extern "C" void kernel_launch(void* const* d_in, const int* in_sizes, int n_in,
                              void* d_out, int out_size, void* d_ws, size_t ws_size,
                              hipStream_t stream)
{
    const float* x  = (const float*)d_in[0];
    const float* Wq = (const float*)d_in[1];
    const float* Wk = (const float*)d_in[2];
    const float* Wv = (const float*)d_in[3];
    const float* Wo = (const float*)d_in[4];

    char* ws = (char*)d_ws;
    float2* rope = (float2*)ws;                        // 512 KiB
    const size_t TEN = (size_t)MROWS * DM;
    const size_t WEL = (size_t)DM * DM;
    bf16_t* xb    = (bf16_t*)(ws + (1 << 19));
    bf16_t* Wqkvt = xb + TEN;                          // [3072][1024] concat
    bf16_t* Wot   = Wqkvt + 3 * WEL;
    bf16_t* Qt    = Wot + WEL;
    bf16_t* Kt    = Qt + TEN;
    bf16_t* Vt    = Kt + TEN;
    bf16_t* Ot    = Vt + TEN;

    rope_table_kernel<<<(SEQ * 32 + 255) / 256, 256, 0, stream>>>(rope);

    cvt_kernel<<<(int)(TEN / 4 / 256), 256, 0, stream>>>(x, xb, (int)TEN);
    wtr_kernel<<<1024, 256, 0, stream>>>(Wq, Wqkvt);
    wtr_kernel<<<1024, 256, 0, stream>>>(Wk, Wqkvt + WEL);
    wtr_kernel<<<1024, 256, 0, stream>>>(Wv, Wqkvt + 2 * WEL);
    wtr_kernel<<<1024, 256, 0, stream>>>(Wo, Wot);

    // merged QKV: 64 m-tiles x 24 n-tiles
    gemm_qkv_kernel<<<64 * 24, 256, 0, stream>>>(xb, Wqkvt, Qt, Kt, Vt, rope);

    attn_kernel<<<dim3(8, NB * NH), 256, 0, stream>>>(Qt, Kt, Vt, Ot);

    gemm_out_kernel<<<64 * 8, 256, 0, stream>>>(Ot, Wot, (float*)d_out);
}

// Round 6
// 338.311 us; speedup vs baseline: 2.7388x; 1.1602x over previous
//
#include <hip/hip_runtime.h>
#include <hip/hip_bf16.h>

// Problem constants: B=4, S=2048, D=1024, H=16, dk=64
#define SEQ   2048
#define NB    4
#define NH    16
#define DK    64
#define DM    1024
#define MROWS (NB * SEQ)   // 8192

typedef __bf16 bf16_t;
typedef __bf16 bf16x8 __attribute__((ext_vector_type(8)));
typedef __bf16 bf16x4 __attribute__((ext_vector_type(4)));
typedef float  f32x4  __attribute__((ext_vector_type(4)));

#define MFMA16(a, b, c) __builtin_amdgcn_mfma_f32_16x16x32_bf16((a), (b), (c), 0, 0, 0)

// async global->LDS, 16B per lane; LDS dest wave-uniform, HW scatters +lane*16
__device__ __forceinline__ void gl2lds16(const bf16_t* g, bf16_t* l) {
    __builtin_amdgcn_global_load_lds(
        (const __attribute__((address_space(1))) unsigned int*)g,
        (__attribute__((address_space(3))) unsigned int*)l, 16, 0, 0);
}

// ---------------------------------------------------------------------------
// fp32 -> bf16 conversion (x)
// ---------------------------------------------------------------------------
__global__ __launch_bounds__(256) void cvt_kernel(
    const float* __restrict__ in, bf16_t* __restrict__ out, int n)
{
    int i = (blockIdx.x * 256 + threadIdx.x) * 4;
    if (i + 3 < n) {
        const float4 v = *(const float4*)(in + i);
        bf16x4 o;
        o[0] = (bf16_t)v.x; o[1] = (bf16_t)v.y;
        o[2] = (bf16_t)v.z; o[3] = (bf16_t)v.w;
        *(bf16x4*)(out + i) = o;
    }
}

// ---------------------------------------------------------------------------
// Weight transpose + cast: Wt[n][k] = (bf16)W[k][n].  32x32 tiles via LDS.
// ---------------------------------------------------------------------------
__global__ __launch_bounds__(256) void wtr_kernel(
    const float* __restrict__ W, bf16_t* __restrict__ Wt)
{
    __shared__ float T[32][33];
    const int tk0 = (blockIdx.x >> 5) << 5;
    const int tn0 = (blockIdx.x & 31) << 5;
    const int r = threadIdx.x >> 5, c = threadIdx.x & 31;
#pragma unroll
    for (int i = 0; i < 4; ++i)
        T[r + i * 8][c] = W[(size_t)(tk0 + r + i * 8) * DM + tn0 + c];
    __syncthreads();
#pragma unroll
    for (int i = 0; i < 4; ++i)
        Wt[(size_t)(tn0 + r + i * 8) * DM + tk0 + c] = (bf16_t)T[c][r + i * 8];
}

// ---------------------------------------------------------------------------
// RoPE table: tab[s*32+i] = (cos, sin) of s * 10000^(-i/32)
// ---------------------------------------------------------------------------
__global__ void rope_table_kernel(float2* __restrict__ tab) {
    int idx = blockIdx.x * 256 + threadIdx.x;
    if (idx >= SEQ * 32) return;
    int s = idx >> 5, i = idx & 31;
    float freq = powf(10000.0f, -(float)i / 32.0f);
    float a = (float)s * freq;
    tab[idx] = make_float2(cosf(a), sinf(a));
}

// ---------------------------------------------------------------------------
// Double-buffered 128x128xK(BK=32) MFMA K-loop with global_load_lds staging.
// LDS layout: 8 groups of 512 elems per tile; group g holds rows g*16..+15,
// lane i <-> (row i&15, k (i>>4)*8), so frags are lane-contiguous b128 reads.
// One barrier per iter: prefetch buf[nxt] issued right after barrier, compute
// on buf[cur] hides the load latency before next barrier's vmcnt drain.
// TR is compile-time: swaps MFMA operands to produce C^T (for V epilogue).
// ---------------------------------------------------------------------------
template<bool TR>
__device__ __forceinline__ void kloop128(
    const bf16_t* __restrict__ Xp, const bf16_t* __restrict__ Wp,
    bf16_t* As, bf16_t* Bs, int tid, f32x4 (&acc)[4][4], int kiters)
{
    const int lane = tid & 63;
    const int wave = tid >> 6;
    const int wm = wave & 1, wn = wave >> 1;
    const int l = lane & 15, quad = lane >> 4;
    const int rl = lane & 15;
    const int kf = (lane >> 4) << 3;
    const int gA = wave * 2;

    const bf16_t* xa0 = Xp + (size_t)(gA * 16 + rl) * DM + kf;
    const bf16_t* xa1 = Xp + (size_t)((gA + 1) * 16 + rl) * DM + kf;
    const bf16_t* wb0 = Wp + (size_t)(gA * 16 + rl) * DM + kf;
    const bf16_t* wb1 = Wp + (size_t)((gA + 1) * 16 + rl) * DM + kf;

    // prologue: stage k-chunk 0 into buffer 0
    gl2lds16(xa0, As + gA * 512);
    gl2lds16(xa1, As + (gA + 1) * 512);
    gl2lds16(wb0, Bs + gA * 512);
    gl2lds16(wb1, Bs + (gA + 1) * 512);

    for (int k = 0; k < kiters; ++k) {
        const int cur = k & 1;
        __syncthreads();                    // drains vmcnt: buf[cur] ready
        if (k + 1 < kiters) {               // prefetch next chunk
            const int nxt = cur ^ 1;
            const int ko = (k + 1) * 32;
            gl2lds16(xa0 + ko, As + nxt * 4096 + gA * 512);
            gl2lds16(xa1 + ko, As + nxt * 4096 + (gA + 1) * 512);
            gl2lds16(wb0 + ko, Bs + nxt * 4096 + gA * 512);
            gl2lds16(wb1 + ko, Bs + nxt * 4096 + (gA + 1) * 512);
        }
        const bf16_t* ab = As + cur * 4096;
        const bf16_t* bb = Bs + cur * 4096;
        bf16x8 af[4], bw[4];
#pragma unroll
        for (int a = 0; a < 4; ++a) {
            af[a] = *(const bf16x8*)(ab + (wm * 4 + a) * 512 + (quad * 16 + l) * 8);
            bw[a] = *(const bf16x8*)(bb + (wn * 4 + a) * 512 + (quad * 16 + l) * 8);
        }
#pragma unroll
        for (int a = 0; a < 4; ++a)
#pragma unroll
            for (int b = 0; b < 4; ++b)
                acc[a][b] = TR ? MFMA16(bw[b], af[a], acc[a][b])
                               : MFMA16(af[a], bw[b], acc[a][b]);
    }
}

// ---------------------------------------------------------------------------
// Merged QKV GEMM: C = X(8192x1024) @ Wqkv^T, Wqkv stored [3072][1024].
// Epilogue by n0: n<1024 Q (RoPE*1/8), n<2048 K (RoPE), else V (C^T direct).
// ---------------------------------------------------------------------------
__global__ __launch_bounds__(256) void gemm_qkv_kernel(
    const bf16_t* __restrict__ X, const bf16_t* __restrict__ Wt,
    bf16_t* __restrict__ Qt, bf16_t* __restrict__ Kt, bf16_t* __restrict__ Vtr,
    const float2* __restrict__ rope)
{
    __shared__ __align__(16) bf16_t As[2 * 128 * 32];
    __shared__ __align__(16) bf16_t Bs[2 * 128 * 32];

    const int tid  = threadIdx.x;
    const int lane = tid & 63;
    const int wave = tid >> 6;
    const int wm   = wave & 1, wn = wave >> 1;
    const int l    = lane & 15;
    const int quad = lane >> 4;

    const int m0 = (blockIdx.x / 24) << 7;
    const int n0 = (blockIdx.x % 24) << 7;
    const bool tr = (n0 >= 2 * DM);   // V range

    f32x4 acc[4][4] = {};
    if (tr) kloop128<true >(X + (size_t)m0 * DM, Wt + (size_t)n0 * DM, As, Bs, tid, acc, DM / 32);
    else    kloop128<false>(X + (size_t)m0 * DM, Wt + (size_t)n0 * DM, As, Bs, tid, acc, DM / 32);

#pragma unroll
    for (int a = 0; a < 4; ++a)
#pragma unroll
        for (int b = 0; b < 4; ++b)
#pragma unroll
            for (int r = 0; r < 4; ++r) {
                float v = acc[a][b][r];
                if (tr) {
                    const int n = n0 + wn * 64 + b * 16 + quad * 4 + r;
                    const int m = m0 + wm * 64 + a * 16 + l;
                    const int bi = m >> 11, s = m & (SEQ - 1);
                    const int col = n & (DM - 1);
                    const int h = col >> 6, d = col & (DK - 1);
                    Vtr[(((size_t)(bi * NH + h)) * DK + d) * SEQ + s] = (bf16_t)v;
                } else {
                    const int m  = m0 + wm * 64 + a * 16 + quad * 4 + r;
                    const int nn = n0 + wn * 64 + b * 16 + l;
                    const int bi = m >> 11, s = m & (SEQ - 1);
                    const int col = nn & (DM - 1);
                    const int h = col >> 6, d = col & (DK - 1);
                    float pv = __shfl_xor(v, 1);
                    float2 cs = rope[s * 32 + (d >> 1)];
                    float res = (d & 1) ? (v * cs.x + pv * cs.y)
                                        : (v * cs.x - pv * cs.y);
                    bf16_t* dst = (nn < DM) ? Qt : Kt;
                    if (nn < DM) res *= 0.125f;   // fold 1/sqrt(dk) into Q
                    dst[(((size_t)(bi * NH + h)) * SEQ + s) * DK + d] = (bf16_t)res;
                }
            }
}

// ---------------------------------------------------------------------------
// Output projection GEMM: d_out(fp32) = Ot(8192x1024,bf16) @ Wot^T.
// ---------------------------------------------------------------------------
__global__ __launch_bounds__(256) void gemm_out_kernel(
    const bf16_t* __restrict__ X, const bf16_t* __restrict__ Wt,
    float* __restrict__ out)
{
    __shared__ __align__(16) bf16_t As[2 * 128 * 32];
    __shared__ __align__(16) bf16_t Bs[2 * 128 * 32];

    const int tid  = threadIdx.x;
    const int lane = tid & 63;
    const int wave = tid >> 6;
    const int wm   = wave & 1, wn = wave >> 1;
    const int l    = lane & 15;
    const int quad = lane >> 4;

    const int m0 = (blockIdx.x >> 3) << 7;
    const int n0 = (blockIdx.x & 7) << 7;

    f32x4 acc[4][4] = {};
    kloop128<false>(X + (size_t)m0 * DM, Wt + (size_t)n0 * DM, As, Bs, tid, acc, DM / 32);

#pragma unroll
    for (int a = 0; a < 4; ++a)
#pragma unroll
        for (int b = 0; b < 4; ++b)
#pragma unroll
            for (int r = 0; r < 4; ++r) {
                const int m  = m0 + wm * 64 + a * 16 + quad * 4 + r;
                const int nn = n0 + wn * 64 + b * 16 + l;
                out[(size_t)m * DM + nn] = acc[a][b][r];
            }
}

// ---------------------------------------------------------------------------
// Causal flash attention (unchanged from round 4/5).
// ---------------------------------------------------------------------------
#define KLD 72   // LDS row stride (elems): 144 B

__global__ __launch_bounds__(256) void attn_kernel(
    const bf16_t* __restrict__ Q, const bf16_t* __restrict__ K,
    const bf16_t* __restrict__ Vt, bf16_t* __restrict__ O)
{
    __shared__ __align__(16) bf16_t Kl[64 * KLD];
    __shared__ __align__(16) bf16_t Vl[64 * KLD];
    __shared__ __align__(16) bf16_t Pl[4][32 * KLD];

    const int bh   = blockIdx.y;
    const int tid  = threadIdx.x;
    const int wave = tid >> 6;
    const int lane = tid & 63;
    const int l    = lane & 15;
    const int quad = lane >> 4;
    const int srow = tid >> 3;
    const int sch  = (tid & 7) << 3;

    bf16_t* Pw = Pl[wave];
    const bf16_t* Qb = Q  + (size_t)bh * SEQ * DK;
    const bf16_t* Kb = K  + (size_t)bh * SEQ * DK;
    const bf16_t* Vb = Vt + (size_t)bh * DK * SEQ;
    const int b = bh >> 4, h = bh & 15;

    for (int ph = 0; ph < 2; ++ph) {
        const int qblk = ph ? (15 - (int)blockIdx.x) : (int)blockIdx.x;
        const int q0w  = qblk * 128 + wave * 32;
        const int nch  = 2 * (qblk + 1);

        bf16x8 qb[2][2];
#pragma unroll
        for (int u = 0; u < 2; ++u) {
            qb[u][0] = *(const bf16x8*)(Qb + (size_t)(q0w + u * 16 + l) * DK + quad * 8);
            qb[u][1] = *(const bf16x8*)(Qb + (size_t)(q0w + u * 16 + l) * DK + 32 + quad * 8);
        }

        float m_run[2] = {-3e38f, -3e38f};
        float l_run[2] = {0.f, 0.f};
        f32x4 o[4][2] = {};

        bf16x8 pk0 = *(const bf16x8*)(Kb + (size_t)srow * DK + sch);
        bf16x8 pk1 = *(const bf16x8*)(Kb + (size_t)(32 + srow) * DK + sch);
        bf16x8 pv0 = *(const bf16x8*)(Vb + (size_t)srow * SEQ + sch);
        bf16x8 pv1 = *(const bf16x8*)(Vb + (size_t)(32 + srow) * SEQ + sch);

        for (int i = 0; i < nch; ++i) {
            const int c = i * 64;
            __syncthreads();
            *(bf16x8*)(Kl + srow * KLD + sch)        = pk0;
            *(bf16x8*)(Kl + (32 + srow) * KLD + sch) = pk1;
            *(bf16x8*)(Vl + srow * KLD + sch)        = pv0;
            *(bf16x8*)(Vl + (32 + srow) * KLD + sch) = pv1;
            __syncthreads();
            if (i + 1 < nch) {
                const int cn = c + 64;
                pk0 = *(const bf16x8*)(Kb + (size_t)(cn + srow) * DK + sch);
                pk1 = *(const bf16x8*)(Kb + (size_t)(cn + 32 + srow) * DK + sch);
                pv0 = *(const bf16x8*)(Vb + (size_t)srow * SEQ + cn + sch);
                pv1 = *(const bf16x8*)(Vb + (size_t)(32 + srow) * SEQ + cn + sch);
            }
            if (c > q0w + 31) continue;

            f32x4 st[4][2] = {};
#pragma unroll
            for (int t = 0; t < 4; ++t) {
                const bf16x8 k0 = *(const bf16x8*)(Kl + (t * 16 + l) * KLD + quad * 8);
                const bf16x8 k1 = *(const bf16x8*)(Kl + (t * 16 + l) * KLD + 32 + quad * 8);
                st[t][0] = MFMA16(k0, qb[0][0], st[t][0]);
                st[t][0] = MFMA16(k1, qb[0][1], st[t][0]);
                st[t][1] = MFMA16(k0, qb[1][0], st[t][1]);
                st[t][1] = MFMA16(k1, qb[1][1], st[t][1]);
            }
            if (c + 63 > q0w) {
#pragma unroll
                for (int u = 0; u < 2; ++u) {
                    const int thr = q0w + u * 16 + l - c - quad * 4;
#pragma unroll
                    for (int t = 0; t < 4; ++t)
#pragma unroll
                        for (int r = 0; r < 4; ++r)
                            if (t * 16 + r > thr) st[t][u][r] = -3e38f;
                }
            }
#pragma unroll
            for (int u = 0; u < 2; ++u) {
                float cmax = -3e38f;
#pragma unroll
                for (int t = 0; t < 4; ++t)
#pragma unroll
                    for (int r = 0; r < 4; ++r)
                        cmax = fmaxf(cmax, st[t][u][r]);
                cmax = fmaxf(cmax, __shfl_xor(cmax, 16));
                cmax = fmaxf(cmax, __shfl_xor(cmax, 32));
                const float mnew  = fmaxf(m_run[u], cmax);
                const float alpha = __expf(m_run[u] - mnew);
                m_run[u] = mnew;
                float csum = 0.f;
#pragma unroll
                for (int t = 0; t < 4; ++t)
#pragma unroll
                    for (int r = 0; r < 4; ++r) {
                        st[t][u][r] = __expf(st[t][u][r] - mnew);
                        csum += st[t][u][r];
                    }
                csum += __shfl_xor(csum, 16);
                csum += __shfl_xor(csum, 32);
                l_run[u] = l_run[u] * alpha + csum;
#pragma unroll
                for (int n = 0; n < 4; ++n)
#pragma unroll
                    for (int r = 0; r < 4; ++r)
                        o[n][u][r] *= alpha;
#pragma unroll
                for (int t = 0; t < 4; ++t) {
                    bf16x4 pk;
                    pk[0] = (bf16_t)st[t][u][0]; pk[1] = (bf16_t)st[t][u][1];
                    pk[2] = (bf16_t)st[t][u][2]; pk[3] = (bf16_t)st[t][u][3];
                    *(bf16x4*)(Pw + (u * 16 + l) * KLD + t * 16 + quad * 4) = pk;
                }
            }
            const bf16x8 pb00 = *(const bf16x8*)(Pw + l * KLD + quad * 8);
            const bf16x8 pb01 = *(const bf16x8*)(Pw + l * KLD + 32 + quad * 8);
            const bf16x8 pb10 = *(const bf16x8*)(Pw + (16 + l) * KLD + quad * 8);
            const bf16x8 pb11 = *(const bf16x8*)(Pw + (16 + l) * KLD + 32 + quad * 8);
#pragma unroll
            for (int n = 0; n < 4; ++n) {
                const bf16x8 v0 = *(const bf16x8*)(Vl + (n * 16 + l) * KLD + quad * 8);
                const bf16x8 v1 = *(const bf16x8*)(Vl + (n * 16 + l) * KLD + 32 + quad * 8);
                o[n][0] = MFMA16(v0, pb00, o[n][0]);
                o[n][0] = MFMA16(v1, pb01, o[n][0]);
                o[n][1] = MFMA16(v0, pb10, o[n][1]);
                o[n][1] = MFMA16(v1, pb11, o[n][1]);
            }
        }

#pragma unroll
        for (int u = 0; u < 2; ++u) {
            const float inv = 1.0f / l_run[u];
#pragma unroll
            for (int n = 0; n < 4; ++n) {
                bf16x4 ov;
                ov[0] = (bf16_t)(o[n][u][0] * inv); ov[1] = (bf16_t)(o[n][u][1] * inv);
                ov[2] = (bf16_t)(o[n][u][2] * inv); ov[3] = (bf16_t)(o[n][u][3] * inv);
                *(bf16x4*)(Pw + (u * 16 + l) * KLD + n * 16 + quad * 4) = ov;
            }
        }
        const int row  = lane >> 1;
        const int half = (lane & 1) * 32;
        const bf16x8 w0 = *(const bf16x8*)(Pw + row * KLD + half);
        const bf16x8 w1 = *(const bf16x8*)(Pw + row * KLD + half + 8);
        const bf16x8 w2 = *(const bf16x8*)(Pw + row * KLD + half + 16);
        const bf16x8 w3 = *(const bf16x8*)(Pw + row * KLD + half + 24);
        bf16_t* op = O + ((size_t)(b * SEQ + qblk * 128 + wave * 32 + row)) * DM
                       + h * DK + half;
        *(bf16x8*)(op)      = w0;
        *(bf16x8*)(op + 8)  = w1;
        *(bf16x8*)(op + 16) = w2;
        *(bf16x8*)(op + 24) = w3;
    }
}

// ---------------------------------------------------------------------------
extern "C" void kernel_launch(void* const* d_in, const int* in_sizes, int n_in,
                              void* d_out, int out_size, void* d_ws, size_t ws_size,
                              hipStream_t stream)
{
    const float* x  = (const float*)d_in[0];
    const float* Wq = (const float*)d_in[1];
    const float* Wk = (const float*)d_in[2];
    const float* Wv = (const float*)d_in[3];
    const float* Wo = (const float*)d_in[4];

    char* ws = (char*)d_ws;
    float2* rope = (float2*)ws;                        // 512 KiB
    const size_t TEN = (size_t)MROWS * DM;
    const size_t WEL = (size_t)DM * DM;
    bf16_t* xb    = (bf16_t*)(ws + (1 << 19));
    bf16_t* Wqkvt = xb + TEN;                          // [3072][1024] concat
    bf16_t* Wot   = Wqkvt + 3 * WEL;
    bf16_t* Qt    = Wot + WEL;
    bf16_t* Kt    = Qt + TEN;
    bf16_t* Vt    = Kt + TEN;
    bf16_t* Ot    = Vt + TEN;

    rope_table_kernel<<<(SEQ * 32 + 255) / 256, 256, 0, stream>>>(rope);

    cvt_kernel<<<(int)(TEN / 4 / 256), 256, 0, stream>>>(x, xb, (int)TEN);
    wtr_kernel<<<1024, 256, 0, stream>>>(Wq, Wqkvt);
    wtr_kernel<<<1024, 256, 0, stream>>>(Wk, Wqkvt + WEL);
    wtr_kernel<<<1024, 256, 0, stream>>>(Wv, Wqkvt + 2 * WEL);
    wtr_kernel<<<1024, 256, 0, stream>>>(Wo, Wot);

    // merged QKV: 64 m-tiles x 24 n-tiles
    gemm_qkv_kernel<<<64 * 24, 256, 0, stream>>>(xb, Wqkvt, Qt, Kt, Vt, rope);

    attn_kernel<<<dim3(8, NB * NH), 256, 0, stream>>>(Qt, Kt, Vt, Ot);

    gemm_out_kernel<<<64 * 8, 256, 0, stream>>>(Ot, Wot, (float*)d_out);
}